// Round 4
// baseline (837.853 us; speedup 1.0000x reference)
//
#include <hip/hip_runtime.h>
#include <hip/hip_bf16.h>

// NNUE fused: C = clip(stacked_emb @ acc_w^T + acc_b, 0, 6); out[b] = sum_d C * out_w[sel[b]] + out_b[sel[b]]
// M = 32768 (stm rows 0..16383, nstm 16384..32767), K = 768, N = 1024.
// Grid 2048 = 8 XCD-groups x 256. XCD-local swizzle: blockIdx = 8t+x -> XCD x
// owns mb in [32x, 32x+32), nb = t&7 fastest => A-panel fetched once per XCD-L2.
// 256 thr / 4 waves, tile 128x128, BK=64, single LDS buffer (32 KiB) -> 5 blocks/CU.

#define INPUTSZ 768
#define ACCSZ   1024
#define NROWS   16384

typedef __bf16 bf16x8  __attribute__((ext_vector_type(8)));
typedef __bf16 bf16x4v __attribute__((ext_vector_type(4)));
typedef float  f32x4   __attribute__((ext_vector_type(4)));

__global__ void init_out(const int* __restrict__ sel, const float* __restrict__ out_b,
                         float* __restrict__ out) {
    int i = blockIdx.x * 256 + threadIdx.x;
    out[i] = out_b[sel[i]];
}

__global__ __launch_bounds__(256, 5) void nnue_fused(
    const float* __restrict__ stm, const float* __restrict__ nstm,
    const int* __restrict__ sel, const float* __restrict__ acc_w,
    const float* __restrict__ acc_b, const float* __restrict__ out_w,
    float* __restrict__ out)
{
    // 32 KiB LDS total -> LDS allows 5 blocks/CU; VGPR cap 102 allows 5 waves/SIMD
    __shared__ alignas(16) __bf16 As[128 * 64];
    __shared__ alignas(16) __bf16 Bs[128 * 64];

    const int tid  = threadIdx.x;
    const int flat = blockIdx.x;
    // XCD-local decomposition (XCD = blockIdx % 8 round-robin assumption; 2048 % 8 == 0)
    const int x  = flat & 7;          // XCD id
    const int t  = flat >> 3;         // 0..255 within XCD
    const int mb = x * 32 + (t >> 3); // M-tile 0..255, contiguous range per XCD
    const int nb = t & 7;             // N-tile 0..7, fastest within XCD

    const int lane = tid & 63;
    const int w    = tid >> 6;
    const int wr   = w >> 1, wc = w & 1;
    const int l15  = lane & 15, l4 = lane >> 4;

    // A source: rows mb*128..+128 of virtual stacked matrix (128 | 16384, no straddle)
    const float* Aptr = (mb < 128) ? stm : nstm;
    const float4* Asrc = (const float4*)Aptr + (size_t)(mb & 127) * 128 * (INPUTSZ / 4);
    const float4* Bsrc = (const float4*)acc_w + (size_t)nb * 128 * (INPUTSZ / 4);

    float4 ra[8], rb[8];
    // prologue: K-tile 0 into regs
#pragma unroll
    for (int p = 0; p < 8; ++p) {
        int i = tid + p * 256;
        int r = i >> 4, c = i & 15;            // row 0..127, float4-chunk 0..15
        ra[p] = Asrc[r * (INPUTSZ / 4) + c];
        rb[p] = Bsrc[r * (INPUTSZ / 4) + c];
    }

    f32x4 acc[4][4];
#pragma unroll
    for (int mt = 0; mt < 4; ++mt)
#pragma unroll
        for (int nt = 0; nt < 4; ++nt) {
            f32x4 z = {0.f, 0.f, 0.f, 0.f};
            acc[mt][nt] = z;
        }

    for (int kb = 0; kb < 12; ++kb) {
        if (kb)
            __syncthreads();   // all waves done reading LDS for tile kb-1
        // convert + store staged regs (tile kb), XOR-swizzled (8x16B slots, conflict-free)
#pragma unroll
        for (int p = 0; p < 8; ++p) {
            int i = tid + p * 256;
            int r = i >> 4, c = i & 15;
            int ke = (c * 4) ^ ((r & 7) << 3);  // element offset within 64-wide row
            bf16x4v va; va[0] = (__bf16)ra[p].x; va[1] = (__bf16)ra[p].y;
                        va[2] = (__bf16)ra[p].z; va[3] = (__bf16)ra[p].w;
            *(bf16x4v*)&As[r * 64 + ke] = va;
            bf16x4v vb; vb[0] = (__bf16)rb[p].x; vb[1] = (__bf16)rb[p].y;
                        vb[2] = (__bf16)rb[p].z; vb[3] = (__bf16)rb[p].w;
            *(bf16x4v*)&Bs[r * 64 + ke] = vb;
        }
        // issue next tile's global loads; latency hides under barrier + MFMA phase
        if (kb < 11) {
#pragma unroll
            for (int p = 0; p < 8; ++p) {
                int i = tid + p * 256;
                int r = i >> 4, c = i & 15;
                ra[p] = Asrc[r * (INPUTSZ / 4) + (kb + 1) * 16 + c];
                rb[p] = Bsrc[r * (INPUTSZ / 4) + (kb + 1) * 16 + c];
            }
        }
        __syncthreads();   // LDS writes visible

        // compute: 2 K-steps of 32, 4x4 fragment tiles per wave
#pragma unroll
        for (int kt = 0; kt < 2; ++kt) {
            bf16x8 af[4], bfr[4];
#pragma unroll
            for (int mt = 0; mt < 4; ++mt) {
                int arow = wr * 64 + mt * 16 + l15;
                int ke = (kt * 32 + l4 * 8) ^ ((arow & 7) << 3);
                af[mt] = *(const bf16x8*)&As[arow * 64 + ke];
            }
#pragma unroll
            for (int nt = 0; nt < 4; ++nt) {
                int brow = wc * 64 + nt * 16 + l15;
                int ke = (kt * 32 + l4 * 8) ^ ((brow & 7) << 3);
                bfr[nt] = *(const bf16x8*)&Bs[brow * 64 + ke];
            }
#pragma unroll
            for (int mt = 0; mt < 4; ++mt)
#pragma unroll
                for (int nt = 0; nt < 4; ++nt)
                    acc[mt][nt] = __builtin_amdgcn_mfma_f32_16x16x32_bf16(
                        af[mt], bfr[nt], acc[mt][nt], 0, 0, 0);
        }
    }

    // ---- fused epilogue: bias, clip, layer-2 dot, reduce, atomic accumulate ----
    float biasv[4];
#pragma unroll
    for (int nt = 0; nt < 4; ++nt)
        biasv[nt] = acc_b[nb * 128 + wc * 64 + nt * 16 + l15];

#pragma unroll
    for (int mt = 0; mt < 4; ++mt) {
#pragma unroll
        for (int r = 0; r < 4; ++r) {
            int row_local = wr * 64 + mt * 16 + l4 * 4 + r;   // C/D: row = 4*(lane>>4)+reg
            int grow = mb * 128 + row_local;
            int half = grow >> 14;            // 0 = stm, 1 = nstm
            int b    = grow & (NROWS - 1);
            int s    = sel[b];
            const float* w2r = out_w + (size_t)s * (2 * ACCSZ) + half * ACCSZ
                               + nb * 128 + wc * 64;
            float ps = 0.f;
#pragma unroll
            for (int nt = 0; nt < 4; ++nt) {
                float v = acc[mt][nt][r] + biasv[nt];
                v = fminf(fmaxf(v, 0.f), 6.f);
                ps += v * w2r[nt * 16 + l15];
            }
            // reduce across the 16 column-lanes (same l4 group)
            ps += __shfl_xor(ps, 1, 64);
            ps += __shfl_xor(ps, 2, 64);
            ps += __shfl_xor(ps, 4, 64);
            ps += __shfl_xor(ps, 8, 64);
            if (l15 == 0)
                atomicAdd(&out[b], ps);
        }
    }
}

extern "C" void kernel_launch(void* const* d_in, const int* in_sizes, int n_in,
                              void* d_out, int out_size, void* d_ws, size_t ws_size,
                              hipStream_t stream) {
    const float* stm  = (const float*)d_in[0];
    const float* nstm = (const float*)d_in[1];
    const int*   sel  = (const int*)d_in[2];
    const float* accw = (const float*)d_in[3];
    const float* accb = (const float*)d_in[4];
    const float* outw = (const float*)d_in[5];
    const float* outb = (const float*)d_in[6];
    float* out = (float*)d_out;

    // d_out is re-poisoned before every launch: seed with out_b[sel[b]]
    init_out<<<NROWS / 256, 256, 0, stream>>>(sel, outb, out);
    nnue_fused<<<2048, 256, 0, stream>>>(stm, nstm, sel, accw, accb, outw, out);
}

// Round 5
// 243.881 us; speedup vs baseline: 3.4355x; 3.4355x over previous
//
#include <hip/hip_runtime.h>
#include <hip/hip_bf16.h>

// NNUE fused: C = clip(stacked_emb @ acc_w^T + acc_b, 0, 6); out[b] = sum_d C * out_w[sel[b]] + out_b[sel[b]]
// M = 32768 (stm rows 0..16383, nstm 16384..32767), K = 768, N = 1024.
// Grid 2048 = 8 XCD-groups x 256. XCD-local swizzle: blockIdx = 8t+x -> XCD x
// owns mb in [32x, 32x+32), nb = t&7 fastest => A-panel fetched once per XCD-L2.
// 256 thr / 4 waves, tile 128x128, BK=64, single LDS buffer (32 KiB).
// launch_bounds(256,3): VGPR cap ~170 >= ~160 demand (64 stage + 64 acc + addr)
// -> NO SPILL. Round-4's (256,5) capped at 102 and spilled 2.5 GB of scratch.

#define INPUTSZ 768
#define ACCSZ   1024
#define NROWS   16384

typedef __bf16 bf16x8  __attribute__((ext_vector_type(8)));
typedef __bf16 bf16x4v __attribute__((ext_vector_type(4)));
typedef float  f32x4   __attribute__((ext_vector_type(4)));

__global__ void init_out(const int* __restrict__ sel, const float* __restrict__ out_b,
                         float* __restrict__ out) {
    int i = blockIdx.x * 256 + threadIdx.x;
    out[i] = out_b[sel[i]];
}

__global__ __launch_bounds__(256, 3) void nnue_fused(
    const float* __restrict__ stm, const float* __restrict__ nstm,
    const int* __restrict__ sel, const float* __restrict__ acc_w,
    const float* __restrict__ acc_b, const float* __restrict__ out_w,
    float* __restrict__ out)
{
    // 32 KiB LDS total -> LDS allows 5 blocks/CU; binding limit is VGPR (3 waves/SIMD)
    __shared__ alignas(16) __bf16 As[128 * 64];
    __shared__ alignas(16) __bf16 Bs[128 * 64];

    const int tid  = threadIdx.x;
    const int flat = blockIdx.x;
    // XCD-local decomposition (XCD = blockIdx % 8 round-robin assumption; 2048 % 8 == 0)
    const int x  = flat & 7;          // XCD id
    const int t  = flat >> 3;         // 0..255 within XCD
    const int mb = x * 32 + (t >> 3); // M-tile 0..255, contiguous range per XCD
    const int nb = t & 7;             // N-tile 0..7, fastest within XCD

    const int lane = tid & 63;
    const int w    = tid >> 6;
    const int wr   = w >> 1, wc = w & 1;
    const int l15  = lane & 15, l4 = lane >> 4;

    // A source: rows mb*128..+128 of virtual stacked matrix (128 | 16384, no straddle)
    const float* Aptr = (mb < 128) ? stm : nstm;
    const float4* Asrc = (const float4*)Aptr + (size_t)(mb & 127) * 128 * (INPUTSZ / 4);
    const float4* Bsrc = (const float4*)acc_w + (size_t)nb * 128 * (INPUTSZ / 4);

    float4 ra[8], rb[8];
    // prologue: K-tile 0 into regs
#pragma unroll
    for (int p = 0; p < 8; ++p) {
        int i = tid + p * 256;
        int r = i >> 4, c = i & 15;            // row 0..127, float4-chunk 0..15
        ra[p] = Asrc[r * (INPUTSZ / 4) + c];
        rb[p] = Bsrc[r * (INPUTSZ / 4) + c];
    }

    f32x4 acc[4][4];
#pragma unroll
    for (int mt = 0; mt < 4; ++mt)
#pragma unroll
        for (int nt = 0; nt < 4; ++nt) {
            f32x4 z = {0.f, 0.f, 0.f, 0.f};
            acc[mt][nt] = z;
        }

    for (int kb = 0; kb < 12; ++kb) {
        if (kb)
            __syncthreads();   // all waves done reading LDS for tile kb-1
        // convert + store staged regs (tile kb), XOR-swizzled (8x16B slots, conflict-free)
#pragma unroll
        for (int p = 0; p < 8; ++p) {
            int i = tid + p * 256;
            int r = i >> 4, c = i & 15;
            int ke = (c * 4) ^ ((r & 7) << 3);  // element offset within 64-wide row
            bf16x4v va; va[0] = (__bf16)ra[p].x; va[1] = (__bf16)ra[p].y;
                        va[2] = (__bf16)ra[p].z; va[3] = (__bf16)ra[p].w;
            *(bf16x4v*)&As[r * 64 + ke] = va;
            bf16x4v vb; vb[0] = (__bf16)rb[p].x; vb[1] = (__bf16)rb[p].y;
                        vb[2] = (__bf16)rb[p].z; vb[3] = (__bf16)rb[p].w;
            *(bf16x4v*)&Bs[r * 64 + ke] = vb;
        }
        // issue next tile's global loads; latency hides under barrier + MFMA phase
        if (kb < 11) {
#pragma unroll
            for (int p = 0; p < 8; ++p) {
                int i = tid + p * 256;
                int r = i >> 4, c = i & 15;
                ra[p] = Asrc[r * (INPUTSZ / 4) + (kb + 1) * 16 + c];
                rb[p] = Bsrc[r * (INPUTSZ / 4) + (kb + 1) * 16 + c];
            }
        }
        __syncthreads();   // LDS writes visible

        // compute: 2 K-steps of 32, 4x4 fragment tiles per wave
#pragma unroll
        for (int kt = 0; kt < 2; ++kt) {
            bf16x8 af[4], bfr[4];
#pragma unroll
            for (int mt = 0; mt < 4; ++mt) {
                int arow = wr * 64 + mt * 16 + l15;
                int ke = (kt * 32 + l4 * 8) ^ ((arow & 7) << 3);
                af[mt] = *(const bf16x8*)&As[arow * 64 + ke];
            }
#pragma unroll
            for (int nt = 0; nt < 4; ++nt) {
                int brow = wc * 64 + nt * 16 + l15;
                int ke = (kt * 32 + l4 * 8) ^ ((brow & 7) << 3);
                bfr[nt] = *(const bf16x8*)&Bs[brow * 64 + ke];
            }
#pragma unroll
            for (int mt = 0; mt < 4; ++mt)
#pragma unroll
                for (int nt = 0; nt < 4; ++nt)
                    acc[mt][nt] = __builtin_amdgcn_mfma_f32_16x16x32_bf16(
                        af[mt], bfr[nt], acc[mt][nt], 0, 0, 0);
        }
    }

    // ---- fused epilogue: bias, clip, layer-2 dot, reduce, atomic accumulate ----
    float biasv[4];
#pragma unroll
    for (int nt = 0; nt < 4; ++nt)
        biasv[nt] = acc_b[nb * 128 + wc * 64 + nt * 16 + l15];

#pragma unroll
    for (int mt = 0; mt < 4; ++mt) {
#pragma unroll
        for (int r = 0; r < 4; ++r) {
            int row_local = wr * 64 + mt * 16 + l4 * 4 + r;   // C/D: row = 4*(lane>>4)+reg
            int grow = mb * 128 + row_local;
            int half = grow >> 14;            // 0 = stm, 1 = nstm
            int b    = grow & (NROWS - 1);
            int s    = sel[b];
            const float* w2r = out_w + (size_t)s * (2 * ACCSZ) + half * ACCSZ
                               + nb * 128 + wc * 64;
            float ps = 0.f;
#pragma unroll
            for (int nt = 0; nt < 4; ++nt) {
                float v = acc[mt][nt][r] + biasv[nt];
                v = fminf(fmaxf(v, 0.f), 6.f);
                ps += v * w2r[nt * 16 + l15];
            }
            // reduce across the 16 column-lanes (same l4 group)
            ps += __shfl_xor(ps, 1, 64);
            ps += __shfl_xor(ps, 2, 64);
            ps += __shfl_xor(ps, 4, 64);
            ps += __shfl_xor(ps, 8, 64);
            if (l15 == 0)
                atomicAdd(&out[b], ps);
        }
    }
}

extern "C" void kernel_launch(void* const* d_in, const int* in_sizes, int n_in,
                              void* d_out, int out_size, void* d_ws, size_t ws_size,
                              hipStream_t stream) {
    const float* stm  = (const float*)d_in[0];
    const float* nstm = (const float*)d_in[1];
    const int*   sel  = (const int*)d_in[2];
    const float* accw = (const float*)d_in[3];
    const float* accb = (const float*)d_in[4];
    const float* outw = (const float*)d_in[5];
    const float* outb = (const float*)d_in[6];
    float* out = (float*)d_out;

    // d_out is re-poisoned before every launch: seed with out_b[sel[b]]
    init_out<<<NROWS / 256, 256, 0, stream>>>(sel, outb, out);
    nnue_fused<<<2048, 256, 0, stream>>>(stm, nstm, sel, accw, accb, outw, out);
}

// Round 6
// 227.493 us; speedup vs baseline: 3.6830x; 1.0720x over previous
//
#include <hip/hip_runtime.h>
#include <hip/hip_bf16.h>

// NNUE fused: C = clip(stacked_emb @ acc_w^T + acc_b, 0, 6); out[b] = sum_d C * out_w[sel[b]] + out_b[sel[b]]
// M = 32768 (stm rows 0..16383, nstm 16384..32767), K = 768, N = 1024.
// Grid 2048 = 8 XCD-groups x 256; XCD-local swizzle (verified r5: FETCH 400->114 MB).
// r6 changes: (1) epilogue de-atomized -> per-block partials to ws[32768][16] fp32,
// summed by finalize_out (524k same-line device atomics were the ~150us floor suspect);
// (2) prefetch issued AFTER the barrier so the compiler's vmcnt(0)-before-s_barrier
// no longer drains it instantly -> loads overlap the MFMA phase.

#define INPUTSZ 768
#define ACCSZ   1024
#define NROWS   16384

typedef __bf16 bf16x8  __attribute__((ext_vector_type(8)));
typedef __bf16 bf16x4v __attribute__((ext_vector_type(4)));
typedef float  f32x4   __attribute__((ext_vector_type(4)));

__global__ void init_out(const int* __restrict__ sel, const float* __restrict__ out_b,
                         float* __restrict__ out) {   // fallback path only
    int i = blockIdx.x * 256 + threadIdx.x;
    out[i] = out_b[sel[i]];
}

__global__ void finalize_out(const float* __restrict__ ws, const int* __restrict__ sel,
                             const float* __restrict__ out_b, float* __restrict__ out) {
    int b = blockIdx.x * 256 + threadIdx.x;
    const float4* p0 = (const float4*)(ws + (size_t)b * 16);
    const float4* p1 = (const float4*)(ws + (size_t)(b + NROWS) * 16);
    float s = out_b[sel[b]];
#pragma unroll
    for (int i = 0; i < 4; ++i) { float4 v = p0[i]; s += v.x + v.y + v.z + v.w; }
#pragma unroll
    for (int i = 0; i < 4; ++i) { float4 v = p1[i]; s += v.x + v.y + v.z + v.w; }
    out[b] = s;
}

template <bool USE_WS>
__global__ __launch_bounds__(256, 3) void nnue_fused(
    const float* __restrict__ stm, const float* __restrict__ nstm,
    const int* __restrict__ sel, const float* __restrict__ acc_w,
    const float* __restrict__ acc_b, const float* __restrict__ out_w,
    float* __restrict__ ws, float* __restrict__ out)
{
    __shared__ alignas(16) __bf16 As[128 * 64];
    __shared__ alignas(16) __bf16 Bs[128 * 64];

    const int tid  = threadIdx.x;
    const int flat = blockIdx.x;
    // XCD-local decomposition (XCD = blockIdx % 8; 2048 % 8 == 0 -> bijective)
    const int x  = flat & 7;
    const int t  = flat >> 3;
    const int mb = x * 32 + (t >> 3);   // M-tile 0..255, contiguous per XCD
    const int nb = t & 7;               // N-tile 0..7, fastest within XCD

    const int lane = tid & 63;
    const int w    = tid >> 6;
    const int wr   = w >> 1, wc = w & 1;
    const int l15  = lane & 15, l4 = lane >> 4;

    const float* Aptr = (mb < 128) ? stm : nstm;
    const float4* Asrc = (const float4*)Aptr + (size_t)(mb & 127) * 128 * (INPUTSZ / 4);
    const float4* Bsrc = (const float4*)acc_w + (size_t)nb * 128 * (INPUTSZ / 4);

    float4 ra[8], rb[8];
#pragma unroll
    for (int p = 0; p < 8; ++p) {
        int i = tid + p * 256;
        int r = i >> 4, c = i & 15;
        ra[p] = Asrc[r * (INPUTSZ / 4) + c];
        rb[p] = Bsrc[r * (INPUTSZ / 4) + c];
    }

    f32x4 acc[4][4];
#pragma unroll
    for (int mt = 0; mt < 4; ++mt)
#pragma unroll
        for (int nt = 0; nt < 4; ++nt) {
            f32x4 z = {0.f, 0.f, 0.f, 0.f};
            acc[mt][nt] = z;
        }

    for (int kb = 0; kb < 12; ++kb) {
        if (kb)
            __syncthreads();   // waves done reading LDS tile kb-1; waits prefetch vmcnt
        // convert + store staged regs (tile kb), XOR-swizzled (8x16B slots, conflict-free)
#pragma unroll
        for (int p = 0; p < 8; ++p) {
            int i = tid + p * 256;
            int r = i >> 4, c = i & 15;
            int ke = (c * 4) ^ ((r & 7) << 3);
            bf16x4v va; va[0] = (__bf16)ra[p].x; va[1] = (__bf16)ra[p].y;
                        va[2] = (__bf16)ra[p].z; va[3] = (__bf16)ra[p].w;
            *(bf16x4v*)&As[r * 64 + ke] = va;
            bf16x4v vb; vb[0] = (__bf16)rb[p].x; vb[1] = (__bf16)rb[p].y;
                        vb[2] = (__bf16)rb[p].z; vb[3] = (__bf16)rb[p].w;
            *(bf16x4v*)&Bs[r * 64 + ke] = vb;
        }
        __syncthreads();   // LDS writes visible; vmcnt already drained -> cheap

        // issue next tile's loads NOW: they fly across the whole MFMA phase
        if (kb < 11) {
#pragma unroll
            for (int p = 0; p < 8; ++p) {
                int i = tid + p * 256;
                int r = i >> 4, c = i & 15;
                ra[p] = Asrc[r * (INPUTSZ / 4) + (kb + 1) * 16 + c];
                rb[p] = Bsrc[r * (INPUTSZ / 4) + (kb + 1) * 16 + c];
            }
        }

        // compute: 2 K-steps of 32, 4x4 fragment tiles per wave
#pragma unroll
        for (int kt = 0; kt < 2; ++kt) {
            bf16x8 af[4], bfr[4];
#pragma unroll
            for (int mt = 0; mt < 4; ++mt) {
                int arow = wr * 64 + mt * 16 + l15;
                int ke = (kt * 32 + l4 * 8) ^ ((arow & 7) << 3);
                af[mt] = *(const bf16x8*)&As[arow * 64 + ke];
            }
#pragma unroll
            for (int nt = 0; nt < 4; ++nt) {
                int brow = wc * 64 + nt * 16 + l15;
                int ke = (kt * 32 + l4 * 8) ^ ((brow & 7) << 3);
                bfr[nt] = *(const bf16x8*)&Bs[brow * 64 + ke];
            }
#pragma unroll
            for (int mt = 0; mt < 4; ++mt)
#pragma unroll
                for (int nt = 0; nt < 4; ++nt)
                    acc[mt][nt] = __builtin_amdgcn_mfma_f32_16x16x32_bf16(
                        af[mt], bfr[nt], acc[mt][nt], 0, 0, 0);
        }
    }

    // ---- fused epilogue: bias, clip, layer-2 dot, lane-group reduce ----
    float biasv[4];
#pragma unroll
    for (int nt = 0; nt < 4; ++nt)
        biasv[nt] = acc_b[nb * 128 + wc * 64 + nt * 16 + l15];

    const int pidx = nb * 2 + wc;   // partial slot 0..15

#pragma unroll
    for (int mt = 0; mt < 4; ++mt) {
#pragma unroll
        for (int r = 0; r < 4; ++r) {
            int row_local = wr * 64 + mt * 16 + l4 * 4 + r;   // C/D: row = 4*(lane>>4)+reg
            int grow = mb * 128 + row_local;
            int half = grow >> 14;
            int b    = grow & (NROWS - 1);
            int s    = sel[b];
            const float* w2r = out_w + (size_t)s * (2 * ACCSZ) + half * ACCSZ
                               + nb * 128 + wc * 64;
            float ps = 0.f;
#pragma unroll
            for (int nt = 0; nt < 4; ++nt) {
                float v = acc[mt][nt][r] + biasv[nt];
                v = fminf(fmaxf(v, 0.f), 6.f);
                ps += v * w2r[nt * 16 + l15];
            }
            ps += __shfl_xor(ps, 1, 64);
            ps += __shfl_xor(ps, 2, 64);
            ps += __shfl_xor(ps, 4, 64);
            ps += __shfl_xor(ps, 8, 64);
            if (l15 == 0) {
                if (USE_WS)
                    ws[(size_t)grow * 16 + pidx] = ps;   // plain store, slot written once
                else
                    atomicAdd(&out[b], ps);              // fallback (ws too small)
            }
        }
    }
}

extern "C" void kernel_launch(void* const* d_in, const int* in_sizes, int n_in,
                              void* d_out, int out_size, void* d_ws, size_t ws_size,
                              hipStream_t stream) {
    const float* stm  = (const float*)d_in[0];
    const float* nstm = (const float*)d_in[1];
    const int*   sel  = (const int*)d_in[2];
    const float* accw = (const float*)d_in[3];
    const float* accb = (const float*)d_in[4];
    const float* outw = (const float*)d_in[5];
    const float* outb = (const float*)d_in[6];
    float* out = (float*)d_out;
    float* ws  = (float*)d_ws;

    const size_t ws_need = (size_t)2 * NROWS * 16 * sizeof(float);   // 2 MiB
    if (ws_size >= ws_need) {
        nnue_fused<true><<<2048, 256, 0, stream>>>(stm, nstm, sel, accw, accb, outw, ws, out);
        finalize_out<<<NROWS / 256, 256, 0, stream>>>(ws, sel, outb, out);
    } else {
        init_out<<<NROWS / 256, 256, 0, stream>>>(sel, outb, out);
        nnue_fused<false><<<2048, 256, 0, stream>>>(stm, nstm, sel, accw, accb, outw, ws, out);
    }
}